// Round 1
// baseline (70.777 us; speedup 1.0000x reference)
//
#include <hip/hip_runtime.h>
#include <cstdint>
#include <cstddef>

#define ALPHA_C 0.5
#define SIGMA_INV 10.0f
#define EPS_C 1e-7f

constexpr int TDIM = 512;   // time bins
constexpr int ROWS = 32;    // rows per block in rows_kernel
constexpr int PITCH = 513;  // LDS pitch (f32) -> bank = (row + k) % 32

// Kernel A: per-row cumsum (tree scan), nll, scale=exp(-cdf_at/sigma), bin idx,
// and transposed E[k][i] = exp(cdf[i][k]/sigma) via LDS tile.
__global__ __launch_bounds__(256) void rows_kernel(
    const float* __restrict__ pmf, const float* __restrict__ times,
    const int* __restrict__ events, const float* __restrict__ bins,
    float* __restrict__ E, float* __restrict__ scale, float* __restrict__ nll,
    int* __restrict__ kidx, int N)
{
    __shared__ float lds[ROWS * PITCH];
    const int tid = threadIdx.x;
    const int lane = tid & 63;
    const int wid = tid >> 6;
    const int i0 = blockIdx.x * ROWS;

    for (int rr = 0; rr < ROWS / 4; ++rr) {  // 4 waves, 8 rows each
        const int rl = wid * (ROWS / 4) + rr;
        const int i = i0 + rl;
        const float4* p4 = (const float4*)(pmf + (size_t)i * TDIM + lane * 8);
        float4 a = p4[0];
        float4 b = p4[1];
        float c0 = a.x, c1 = c0 + a.y, c2 = c1 + a.z, c3 = c2 + a.w;
        float c4 = c3 + b.x, c5 = c4 + b.y, c6 = c5 + b.z, c7 = c6 + b.w;
        const float s = c7;
        float v = s;
        #pragma unroll
        for (int d = 1; d < 64; d <<= 1) {
            float u = __shfl_up(v, d);
            if (lane >= d) v += u;
        }
        const float excl = v - s;           // exclusive prefix of lane sums
        const float tot = __shfl(v, 63);    // row total
        const int base = rl * PITCH + lane * 8;
        lds[base + 0] = c0 + excl; lds[base + 1] = c1 + excl;
        lds[base + 2] = c2 + excl; lds[base + 3] = c3 + excl;
        lds[base + 4] = c4 + excl; lds[base + 5] = c5 + excl;
        lds[base + 6] = c6 + excl; lds[base + 7] = c7 + excl;

        if (lane == 0) {
            const float t = times[i];
            // searchsorted(bins, t, side='left'): first idx with bins[idx] >= t
            int lo = 0, hi = TDIM;
            while (lo < hi) {
                int mid = (lo + hi) >> 1;
                if (bins[mid] < t) lo = mid + 1; else hi = mid;
            }
            int k = lo - 1;
            k = k < 0 ? 0 : (k > TDIM - 1 ? TDIM - 1 : k);
            const float cdf_at = lds[rl * PITCH + k];
            const float pmf_at = pmf[(size_t)i * TDIM + k];
            const float surv = tot - cdf_at + pmf_at;
            const float nl = (events[i] == 1) ? -logf(pmf_at + EPS_C)
                                              : -logf(surv + EPS_C);
            nll[i] = nl;
            scale[i] = expf(-cdf_at * SIGMA_INV);
            kidx[i] = k;
        }
    }
    __syncthreads();

    // Transposed write: E[k][i0 + c] = exp(cdf[c][k] / sigma)
    // 32 rows x 512 k = 16384 elems / 256 threads = 64 iters.
    for (int s2 = 0; s2 < (ROWS * TDIM) / 256; ++s2) {
        const int idx = s2 * 256 + tid;
        const int c = idx & (ROWS - 1);
        const int kk = idx >> 5;  // ROWS == 32
        E[(size_t)kk * N + i0 + c] = expf(lds[c * PITCH + kk] * SIGMA_INV);
    }
}

// Kernel B: one block per i; reduce over j of [t_j > t_i] * E[k_i][j].
__global__ __launch_bounds__(256) void pair_kernel(
    const float* __restrict__ E, const float* __restrict__ times,
    const int* __restrict__ events, const int* __restrict__ kidx,
    const float* __restrict__ scale, float* __restrict__ per,
    int* __restrict__ validf, int N)
{
    const int i = blockIdx.x;
    const float ti = times[i];
    const int k = kidx[i];
    const float4* row = (const float4*)(E + (size_t)k * N);
    const float4* t4 = (const float4*)times;

    float sum = 0.f;
    int cnt = 0;
    for (int jj = threadIdx.x; jj < N / 4; jj += 256) {
        float4 e = row[jj];
        float4 tj = t4[jj];
        if (tj.x > ti) { sum += e.x; cnt++; }
        if (tj.y > ti) { sum += e.y; cnt++; }
        if (tj.z > ti) { sum += e.z; cnt++; }
        if (tj.w > ti) { sum += e.w; cnt++; }
    }
    #pragma unroll
    for (int d = 32; d > 0; d >>= 1) {
        sum += __shfl_down(sum, d);
        cnt += __shfl_down(cnt, d);
    }
    __shared__ float wsum[4];
    __shared__ int wcnt[4];
    const int lane = threadIdx.x & 63;
    const int wid = threadIdx.x >> 6;
    if (lane == 0) { wsum[wid] = sum; wcnt[wid] = cnt; }
    __syncthreads();
    if (threadIdx.x == 0) {
        float s = wsum[0] + wsum[1] + wsum[2] + wsum[3];
        int c = wcnt[0] + wcnt[1] + wcnt[2] + wcnt[3];
        bool valid = (events[i] == 1) && (c > 0);
        float pi = scale[i] * s / (float)(c > 0 ? c : 1);
        per[i] = valid ? pi : 0.f;
        validf[i] = valid ? 1 : 0;
    }
}

// Kernel C: final reduction in double; writes the scalar loss.
__global__ __launch_bounds__(1024) void final_kernel(
    const float* __restrict__ nll, const float* __restrict__ per,
    const int* __restrict__ validf, const int* __restrict__ events,
    float* __restrict__ out, int N)
{
    __shared__ double sd1[1024];
    __shared__ double sd2[1024];
    __shared__ int si1[1024];
    __shared__ int si2[1024];
    const int t = threadIdx.x;
    double a = 0.0, b = 0.0;
    int c = 0, d = 0;
    for (int i = t; i < N; i += 1024) {
        a += (double)nll[i];
        b += (double)per[i];
        c += validf[i];
        d += events[i];
    }
    sd1[t] = a; sd2[t] = b; si1[t] = c; si2[t] = d;
    __syncthreads();
    for (int off = 512; off > 0; off >>= 1) {
        if (t < off) {
            sd1[t] += sd1[t + off];
            sd2[t] += sd2[t + off];
            si1[t] += si1[t + off];
            si2[t] += si2[t + off];
        }
        __syncthreads();
    }
    if (t == 0) {
        double loss = sd1[0] / (double)N;
        long long npairs = si1[0];
        long long ev = si2[0];
        if (ev > 1 && npairs > 0) {
            loss += ALPHA_C * sd2[0] / (double)npairs;
        }
        out[0] = (float)loss;
    }
}

extern "C" void kernel_launch(void* const* d_in, const int* in_sizes, int n_in,
                              void* d_out, int out_size, void* d_ws, size_t ws_size,
                              hipStream_t stream) {
    const float* pmf = (const float*)d_in[0];
    const float* times = (const float*)d_in[1];
    const int* events = (const int*)d_in[2];
    const float* bins = (const float*)d_in[3];
    const int N = in_sizes[1];  // 8192

    float* E = (float*)d_ws;                    // TDIM * N
    float* scale = E + (size_t)TDIM * N;        // N
    float* nll = scale + N;                     // N
    float* per = nll + N;                       // N
    int* kidx = (int*)(per + N);                // N
    int* validf = kidx + N;                     // N

    rows_kernel<<<N / ROWS, 256, 0, stream>>>(pmf, times, events, bins,
                                              E, scale, nll, kidx, N);
    pair_kernel<<<N, 256, 0, stream>>>(E, times, events, kidx, scale,
                                       per, validf, N);
    final_kernel<<<1, 1024, 0, stream>>>(nll, per, validf, events,
                                         (float*)d_out, N);
}

// Round 2
// 63.497 us; speedup vs baseline: 1.1146x; 1.1146x over previous
//
#include <hip/hip_runtime.h>
#include <cstdint>
#include <cstddef>

#define ALPHA_C 0.5
#define SIGMA_INV 10.0f
#define EPS_C 1e-7f

constexpr int TDIM = 512;   // time bins
constexpr int NROW = 8192;  // rows
constexpr int ROWS = 32;    // rows per block in rows_kernel
constexpr int PITCH = 513;  // LDS pitch (f32) -> bank = (row + k) % 32
constexpr int MAXCLAIM = 128;

// Kernel A: per-row cumsum (tree scan), nll, scale=exp(-cdf_at/sigma), bin idx,
// and transposed CT[k][i] = cdf[i][k] via LDS tile (exp deferred to col_kernel).
__global__ __launch_bounds__(256) void rows_kernel(
    const float* __restrict__ pmf, const float* __restrict__ times,
    const int* __restrict__ events, const float* __restrict__ bins,
    float* __restrict__ CT, float* __restrict__ scale, float* __restrict__ nll,
    int* __restrict__ kidx, int N)
{
    __shared__ float lds[ROWS * PITCH];
    const int tid = threadIdx.x;
    const int lane = tid & 63;
    const int wid = tid >> 6;
    const int i0 = blockIdx.x * ROWS;

    for (int rr = 0; rr < ROWS / 4; ++rr) {  // 4 waves, 8 rows each
        const int rl = wid * (ROWS / 4) + rr;
        const int i = i0 + rl;
        const float4* p4 = (const float4*)(pmf + (size_t)i * TDIM + lane * 8);
        float4 a = p4[0];
        float4 b = p4[1];
        float c0 = a.x, c1 = c0 + a.y, c2 = c1 + a.z, c3 = c2 + a.w;
        float c4 = c3 + b.x, c5 = c4 + b.y, c6 = c5 + b.z, c7 = c6 + b.w;
        const float s = c7;
        float v = s;
        #pragma unroll
        for (int d = 1; d < 64; d <<= 1) {
            float u = __shfl_up(v, d);
            if (lane >= d) v += u;
        }
        const float excl = v - s;           // exclusive prefix of lane sums
        const float tot = __shfl(v, 63);    // row total
        const int base = rl * PITCH + lane * 8;
        lds[base + 0] = c0 + excl; lds[base + 1] = c1 + excl;
        lds[base + 2] = c2 + excl; lds[base + 3] = c3 + excl;
        lds[base + 4] = c4 + excl; lds[base + 5] = c5 + excl;
        lds[base + 6] = c6 + excl; lds[base + 7] = c7 + excl;

        if (lane == 0) {
            const float t = times[i];
            // searchsorted(bins, t, side='left'): first idx with bins[idx] >= t
            int lo = 0, hi = TDIM;
            while (lo < hi) {
                int mid = (lo + hi) >> 1;
                if (bins[mid] < t) lo = mid + 1; else hi = mid;
            }
            int k = lo - 1;
            k = k < 0 ? 0 : (k > TDIM - 1 ? TDIM - 1 : k);
            const float cdf_at = lds[rl * PITCH + k];
            const float pmf_at = pmf[(size_t)i * TDIM + k];
            const float surv = tot - cdf_at + pmf_at;
            const float nl = (events[i] == 1) ? -logf(pmf_at + EPS_C)
                                              : -logf(surv + EPS_C);
            nll[i] = nl;
            scale[i] = expf(-cdf_at * SIGMA_INV);
            kidx[i] = k;
        }
    }
    __syncthreads();

    // Transposed write: CT[k][i0 + c] = cdf[c][k]
    for (int s2 = 0; s2 < (ROWS * TDIM) / 256; ++s2) {
        const int idx = s2 * 256 + tid;
        const int c = idx & (ROWS - 1);
        const int kk = idx >> 5;  // ROWS == 32
        CT[(size_t)kk * N + i0 + c] = lds[c * PITCH + kk];
    }
}

// Kernel B: one block per k. Stage e[j]=exp(cdf[j][k]/sigma) and times in LDS,
// then for each i with kidx[i]==k do a wave-parallel masked reduction over j.
__global__ __launch_bounds__(512) void col_kernel(
    const float* __restrict__ CT, const float* __restrict__ times,
    const int* __restrict__ events, const int* __restrict__ kidx,
    const float* __restrict__ scale, float* __restrict__ per,
    int* __restrict__ validf, int N)
{
    __shared__ float4 e_lds[NROW / 4];   // 32 KB
    __shared__ float4 t_lds[NROW / 4];   // 32 KB
    __shared__ int claims[MAXCLAIM];
    __shared__ int nclaims;

    const int k = blockIdx.x;
    const int tid = threadIdx.x;
    const int lane = tid & 63;
    const int wid = tid >> 6;          // 8 waves

    if (tid == 0) nclaims = 0;
    __syncthreads();

    const float4* ct4 = (const float4*)(CT + (size_t)k * N);
    const float4* tg4 = (const float4*)times;
    for (int ch = tid; ch < NROW / 4; ch += 512) {
        float4 c = ct4[ch];
        float4 e;
        e.x = expf(c.x * SIGMA_INV);
        e.y = expf(c.y * SIGMA_INV);
        e.z = expf(c.z * SIGMA_INV);
        e.w = expf(c.w * SIGMA_INV);
        e_lds[ch] = e;
        t_lds[ch] = tg4[ch];
    }
    const int4* kx4 = (const int4*)kidx;
    for (int ch = tid; ch < NROW / 4; ch += 512) {
        int4 kx = kx4[ch];
        if (kx.x == k) { int p = atomicAdd(&nclaims, 1); if (p < MAXCLAIM) claims[p] = ch * 4 + 0; }
        if (kx.y == k) { int p = atomicAdd(&nclaims, 1); if (p < MAXCLAIM) claims[p] = ch * 4 + 1; }
        if (kx.z == k) { int p = atomicAdd(&nclaims, 1); if (p < MAXCLAIM) claims[p] = ch * 4 + 2; }
        if (kx.w == k) { int p = atomicAdd(&nclaims, 1); if (p < MAXCLAIM) claims[p] = ch * 4 + 3; }
    }
    __syncthreads();
    const int nc = nclaims;

    const float* tl = (const float*)t_lds;
    for (int c = wid; c < nc; c += 8) {
        const int i = claims[c];
        const float ti = tl[i];
        float sum = 0.f;
        int cnt = 0;
        for (int ch = lane; ch < NROW / 4; ch += 64) {
            float4 e = e_lds[ch];
            float4 t = t_lds[ch];
            if (t.x > ti) { sum += e.x; cnt++; }
            if (t.y > ti) { sum += e.y; cnt++; }
            if (t.z > ti) { sum += e.z; cnt++; }
            if (t.w > ti) { sum += e.w; cnt++; }
        }
        #pragma unroll
        for (int d = 32; d > 0; d >>= 1) {
            sum += __shfl_down(sum, d);
            cnt += __shfl_down(cnt, d);
        }
        if (lane == 0) {
            const bool valid = (events[i] == 1) && (cnt > 0);
            const float pi = scale[i] * sum / (float)(cnt > 0 ? cnt : 1);
            per[i] = valid ? pi : 0.f;
            validf[i] = valid ? 1 : 0;
        }
    }
}

// Kernel C: final reduction in double; writes the scalar loss.
__global__ __launch_bounds__(1024) void final_kernel(
    const float* __restrict__ nll, const float* __restrict__ per,
    const int* __restrict__ validf, const int* __restrict__ events,
    float* __restrict__ out, int N)
{
    __shared__ double sd1[1024];
    __shared__ double sd2[1024];
    __shared__ int si1[1024];
    __shared__ int si2[1024];
    const int t = threadIdx.x;
    double a = 0.0, b = 0.0;
    int c = 0, d = 0;
    for (int i = t; i < N; i += 1024) {
        a += (double)nll[i];
        b += (double)per[i];
        c += validf[i];
        d += events[i];
    }
    sd1[t] = a; sd2[t] = b; si1[t] = c; si2[t] = d;
    __syncthreads();
    for (int off = 512; off > 0; off >>= 1) {
        if (t < off) {
            sd1[t] += sd1[t + off];
            sd2[t] += sd2[t + off];
            si1[t] += si1[t + off];
            si2[t] += si2[t + off];
        }
        __syncthreads();
    }
    if (t == 0) {
        double loss = sd1[0] / (double)N;
        long long npairs = si1[0];
        long long ev = si2[0];
        if (ev > 1 && npairs > 0) {
            loss += ALPHA_C * sd2[0] / (double)npairs;
        }
        out[0] = (float)loss;
    }
}

extern "C" void kernel_launch(void* const* d_in, const int* in_sizes, int n_in,
                              void* d_out, int out_size, void* d_ws, size_t ws_size,
                              hipStream_t stream) {
    const float* pmf = (const float*)d_in[0];
    const float* times = (const float*)d_in[1];
    const int* events = (const int*)d_in[2];
    const float* bins = (const float*)d_in[3];
    const int N = in_sizes[1];  // 8192

    float* CT = (float*)d_ws;                   // TDIM * N
    float* scale = CT + (size_t)TDIM * N;       // N
    float* nll = scale + N;                     // N
    float* per = nll + N;                       // N
    int* kidx = (int*)(per + N);                // N
    int* validf = kidx + N;                     // N

    rows_kernel<<<N / ROWS, 256, 0, stream>>>(pmf, times, events, bins,
                                              CT, scale, nll, kidx, N);
    col_kernel<<<TDIM, 512, 0, stream>>>(CT, times, events, kidx, scale,
                                         per, validf, N);
    final_kernel<<<1, 1024, 0, stream>>>(nll, per, validf, events,
                                         (float*)d_out, N);
}

// Round 3
// 32.131 us; speedup vs baseline: 2.2028x; 1.9762x over previous
//
#include <hip/hip_runtime.h>
#include <cstdint>
#include <cstddef>

#define ALPHA_C 0.5
#define SIGMA_INV 10.0f
#define EPS_C 1e-7f

constexpr int TDIM = 512;   // time bins
constexpr int NROW = 8192;  // rows
constexpr int ROWS = 32;    // rows per block in rows_kernel
constexpr int PITCH = 513;  // LDS pitch (f32) -> bank = (row + k) % 32
constexpr int MAXCLAIM = 256;

// Kernel A: per-row cumsum (tree scan), nll, scale, kidx, and transposed
// CT[k][i] = cdf[i][k] via LDS tile. 8 waves, 4 rows/wave, prefetched.
__global__ __launch_bounds__(512) void rows_kernel(
    const float* __restrict__ pmf, const float* __restrict__ times,
    const int* __restrict__ events, const float* __restrict__ bins,
    float* __restrict__ CT, float* __restrict__ scale, float* __restrict__ nll,
    int* __restrict__ kidx, int N)
{
    __shared__ float lds[ROWS * PITCH];
    const int tid = threadIdx.x;
    const int lane = tid & 63;
    const int wid = tid >> 6;            // 8 waves, 4 rows each
    const int i0 = blockIdx.x * ROWS;

    float4 A[4][2];
    #pragma unroll
    for (int r = 0; r < 4; ++r) {
        const int i = i0 + wid * 4 + r;
        const float4* p4 = (const float4*)(pmf + (size_t)i * TDIM + lane * 8);
        A[r][0] = p4[0];
        A[r][1] = p4[1];
    }
    #pragma unroll
    for (int r = 0; r < 4; ++r) {
        const int rl = wid * 4 + r;
        float c0 = A[r][0].x, c1 = c0 + A[r][0].y, c2 = c1 + A[r][0].z, c3 = c2 + A[r][0].w;
        float c4 = c3 + A[r][1].x, c5 = c4 + A[r][1].y, c6 = c5 + A[r][1].z, c7 = c6 + A[r][1].w;
        float v = c7;
        #pragma unroll
        for (int d = 1; d < 64; d <<= 1) {
            float u = __shfl_up(v, d);
            if (lane >= d) v += u;
        }
        const float excl = v - c7;           // exclusive prefix of lane sums
        const int base = rl * PITCH + lane * 8;
        lds[base + 0] = c0 + excl; lds[base + 1] = c1 + excl;
        lds[base + 2] = c2 + excl; lds[base + 3] = c3 + excl;
        lds[base + 4] = c4 + excl; lds[base + 5] = c5 + excl;
        lds[base + 6] = c6 + excl; lds[base + 7] = c7 + excl;
    }
    __syncthreads();

    // Per-row tail: one thread per row.
    if (tid < ROWS) {
        const int i = i0 + tid;
        const float t = times[i];
        // searchsorted(bins, t, side='left'): first idx with bins[idx] >= t
        int lo = 0, hi = TDIM;
        while (lo < hi) {
            int mid = (lo + hi) >> 1;
            if (bins[mid] < t) lo = mid + 1; else hi = mid;
        }
        int k = lo - 1;
        k = k < 0 ? 0 : (k > TDIM - 1 ? TDIM - 1 : k);
        const float cdf_at = lds[tid * PITCH + k];
        const float tot = lds[tid * PITCH + (TDIM - 1)];
        const float pmf_at = pmf[(size_t)i * TDIM + k];
        const float surv = tot - cdf_at + pmf_at;
        nll[i] = (events[i] == 1) ? -logf(pmf_at + EPS_C) : -logf(surv + EPS_C);
        scale[i] = expf(-cdf_at * SIGMA_INV);
        kidx[i] = k;
    }

    // Transposed write: 512 kk x 8 float4-slots = 4096 slots, 8 per thread.
    #pragma unroll
    for (int s2 = 0; s2 < 8; ++s2) {
        const int idx = s2 * 512 + tid;
        const int slot = idx & 7;
        const int kk = idx >> 3;
        const int c4i = slot * 4;
        float4 v;
        v.x = lds[(c4i + 0) * PITCH + kk];
        v.y = lds[(c4i + 1) * PITCH + kk];
        v.z = lds[(c4i + 2) * PITCH + kk];
        v.w = lds[(c4i + 3) * PITCH + kk];
        *(float4*)(CT + (size_t)kk * N + i0 + c4i) = v;
    }
}

// Kernel B: one block per k. Single masked streaming reduction over the column
// (k_j > k terms), plus an exact O(nc^2) within-bucket correction for the
// ~16 i's with kidx[i] == k.
__global__ __launch_bounds__(256) void col_kernel(
    const float* __restrict__ CT, const float* __restrict__ times,
    const int* __restrict__ events, const int* __restrict__ kidx,
    const float* __restrict__ scale, float* __restrict__ per,
    int* __restrict__ validf, int N)
{
    __shared__ int claim_j[MAXCLAIM];
    __shared__ float claim_t[MAXCLAIM];
    __shared__ float claim_e[MAXCLAIM];
    __shared__ int ord_j[MAXCLAIM];
    __shared__ float ord_t[MAXCLAIM];
    __shared__ float ord_e[MAXCLAIM];
    __shared__ float wsum[4];
    __shared__ int wcnt[4];
    __shared__ int nclaims_sh;
    __shared__ float SGT_sh;
    __shared__ int CGT_sh;

    const int k = blockIdx.x;
    const int tid = threadIdx.x;
    const int lane = tid & 63;
    const int wid = tid >> 6;

    if (tid == 0) nclaims_sh = 0;
    __syncthreads();

    const float4* ct4 = (const float4*)(CT + (size_t)k * N);
    const int4* kx4 = (const int4*)kidx;
    float sum = 0.f;
    int cnt = 0;
    for (int ch = tid; ch < N / 4; ch += 256) {
        const float4 c = ct4[ch];
        const int4 kx = kx4[ch];
        const int j0 = ch * 4;
        if (kx.x > k) { sum += expf(c.x * SIGMA_INV); cnt++; }
        else if (kx.x == k) { int p = atomicAdd(&nclaims_sh, 1); if (p < MAXCLAIM) { claim_j[p] = j0 + 0; claim_t[p] = times[j0 + 0]; claim_e[p] = expf(c.x * SIGMA_INV); } }
        if (kx.y > k) { sum += expf(c.y * SIGMA_INV); cnt++; }
        else if (kx.y == k) { int p = atomicAdd(&nclaims_sh, 1); if (p < MAXCLAIM) { claim_j[p] = j0 + 1; claim_t[p] = times[j0 + 1]; claim_e[p] = expf(c.y * SIGMA_INV); } }
        if (kx.z > k) { sum += expf(c.z * SIGMA_INV); cnt++; }
        else if (kx.z == k) { int p = atomicAdd(&nclaims_sh, 1); if (p < MAXCLAIM) { claim_j[p] = j0 + 2; claim_t[p] = times[j0 + 2]; claim_e[p] = expf(c.z * SIGMA_INV); } }
        if (kx.w > k) { sum += expf(c.w * SIGMA_INV); cnt++; }
        else if (kx.w == k) { int p = atomicAdd(&nclaims_sh, 1); if (p < MAXCLAIM) { claim_j[p] = j0 + 3; claim_t[p] = times[j0 + 3]; claim_e[p] = expf(c.w * SIGMA_INV); } }
    }
    #pragma unroll
    for (int d = 32; d > 0; d >>= 1) {
        sum += __shfl_down(sum, d);
        cnt += __shfl_down(cnt, d);
    }
    if (lane == 0) { wsum[wid] = sum; wcnt[wid] = cnt; }
    __syncthreads();
    if (tid == 0) {
        SGT_sh = (wsum[0] + wsum[1]) + (wsum[2] + wsum[3]);
        CGT_sh = wcnt[0] + wcnt[1] + wcnt[2] + wcnt[3];
    }
    __syncthreads();

    const int nc = nclaims_sh < MAXCLAIM ? nclaims_sh : MAXCLAIM;
    // Rank-reorder claims by j for bit-deterministic summation order.
    if (tid < nc) {
        const int myj = claim_j[tid];
        int rank = 0;
        for (int m = 0; m < nc; ++m) rank += (claim_j[m] < myj) ? 1 : 0;
        ord_j[rank] = myj;
        ord_t[rank] = claim_t[tid];
        ord_e[rank] = claim_e[tid];
    }
    __syncthreads();
    if (tid < nc) {
        const int i = ord_j[tid];
        const float ti = ord_t[tid];
        float s = 0.f;
        int c = 0;
        for (int m = 0; m < nc; ++m) {
            if (ord_t[m] > ti) { s += ord_e[m]; c++; }
        }
        const float S = SGT_sh + s;
        const int C = CGT_sh + c;
        const bool valid = (events[i] == 1) && (C > 0);
        per[i] = valid ? scale[i] * S / (float)(C > 0 ? C : 1) : 0.f;
        validf[i] = valid ? 1 : 0;
    }
}

// Kernel C: final reduction in double; writes the scalar loss.
__global__ __launch_bounds__(1024) void final_kernel(
    const float* __restrict__ nll, const float* __restrict__ per,
    const int* __restrict__ validf, const int* __restrict__ events,
    float* __restrict__ out, int N)
{
    __shared__ double sd1[1024];
    __shared__ double sd2[1024];
    __shared__ int si1[1024];
    __shared__ int si2[1024];
    const int t = threadIdx.x;
    double a = 0.0, b = 0.0;
    int c = 0, d = 0;
    for (int i = t; i < N; i += 1024) {
        a += (double)nll[i];
        b += (double)per[i];
        c += validf[i];
        d += events[i];
    }
    sd1[t] = a; sd2[t] = b; si1[t] = c; si2[t] = d;
    __syncthreads();
    for (int off = 512; off > 0; off >>= 1) {
        if (t < off) {
            sd1[t] += sd1[t + off];
            sd2[t] += sd2[t + off];
            si1[t] += si1[t + off];
            si2[t] += si2[t + off];
        }
        __syncthreads();
    }
    if (t == 0) {
        double loss = sd1[0] / (double)N;
        long long npairs = si1[0];
        long long ev = si2[0];
        if (ev > 1 && npairs > 0) {
            loss += ALPHA_C * sd2[0] / (double)npairs;
        }
        out[0] = (float)loss;
    }
}

extern "C" void kernel_launch(void* const* d_in, const int* in_sizes, int n_in,
                              void* d_out, int out_size, void* d_ws, size_t ws_size,
                              hipStream_t stream) {
    const float* pmf = (const float*)d_in[0];
    const float* times = (const float*)d_in[1];
    const int* events = (const int*)d_in[2];
    const float* bins = (const float*)d_in[3];
    const int N = in_sizes[1];  // 8192

    float* CT = (float*)d_ws;                   // TDIM * N
    float* scale = CT + (size_t)TDIM * N;       // N
    float* nll = scale + N;                     // N
    float* per = nll + N;                       // N
    int* kidx = (int*)(per + N);                // N
    int* validf = kidx + N;                     // N

    rows_kernel<<<N / ROWS, 512, 0, stream>>>(pmf, times, events, bins,
                                              CT, scale, nll, kidx, N);
    col_kernel<<<TDIM, 256, 0, stream>>>(CT, times, events, kidx, scale,
                                         per, validf, N);
    final_kernel<<<1, 1024, 0, stream>>>(nll, per, validf, events,
                                         (float*)d_out, N);
}

// Round 4
// 26.679 us; speedup vs baseline: 2.6529x; 1.2044x over previous
//
#include <hip/hip_runtime.h>
#include <cstdint>
#include <cstddef>

#define SIGMA_INV 10.0f
#define EPS_C 1e-7f

constexpr int TDIM = 512;   // time bins
constexpr int ROWS = 32;    // rows per block in rows_kernel
constexpr int PITCH = 513;  // LDS pitch (f32), conflict-free column reads
constexpr int NB = 256;     // rows_kernel grid = 8192/32
constexpr int MAXC = 256;   // max bucket size (actual ~16, max ~45)

// K1: per-row cumsum (tree scan) into LDS tile; per-row nll/scale/einv/kidx;
// per-block partial SGTp[b][k] = sum_{rows j in block, k < k_j} exp(cdf[j][k]*10).
// Thread tid owns column k=tid exclusively -> register accumulator, no atomics.
__global__ __launch_bounds__(512) void rows_kernel(
    const float* __restrict__ pmf, const float* __restrict__ times,
    const int* __restrict__ events, const float* __restrict__ bins,
    float* __restrict__ SGTp, float* __restrict__ scaleA,
    float* __restrict__ einvA, int* __restrict__ kidxA,
    float* __restrict__ nll_part, int* __restrict__ ev_part, int N)
{
    __shared__ float lds[ROWS * PITCH];   // 65.7 KB
    __shared__ float binsS[TDIM];
    __shared__ int karr[ROWS];
    __shared__ float nllv[ROWS];
    __shared__ int evv[ROWS];
    const int tid = threadIdx.x;
    const int lane = tid & 63;
    const int wid = tid >> 6;            // 8 waves, 4 rows each
    const int i0 = blockIdx.x * ROWS;

    binsS[tid] = bins[tid];              // TDIM == blockDim == 512

    float4 A[4][2];
    #pragma unroll
    for (int r = 0; r < 4; ++r) {
        const int i = i0 + wid * 4 + r;
        const float4* p4 = (const float4*)(pmf + (size_t)i * TDIM + lane * 8);
        A[r][0] = p4[0];
        A[r][1] = p4[1];
    }
    #pragma unroll
    for (int r = 0; r < 4; ++r) {
        const int rl = wid * 4 + r;
        float c0 = A[r][0].x, c1 = c0 + A[r][0].y, c2 = c1 + A[r][0].z, c3 = c2 + A[r][0].w;
        float c4 = c3 + A[r][1].x, c5 = c4 + A[r][1].y, c6 = c5 + A[r][1].z, c7 = c6 + A[r][1].w;
        float v = c7;
        #pragma unroll
        for (int d = 1; d < 64; d <<= 1) {
            float u = __shfl_up(v, d);
            if (lane >= d) v += u;
        }
        const float excl = v - c7;           // exclusive prefix of lane sums
        const int base = rl * PITCH + lane * 8;
        lds[base + 0] = c0 + excl; lds[base + 1] = c1 + excl;
        lds[base + 2] = c2 + excl; lds[base + 3] = c3 + excl;
        lds[base + 4] = c4 + excl; lds[base + 5] = c5 + excl;
        lds[base + 6] = c6 + excl; lds[base + 7] = c7 + excl;
    }
    __syncthreads();

    if (tid < ROWS) {
        const int i = i0 + tid;
        const float t = times[i];
        // searchsorted(bins, t, side='left') on LDS-cached bins
        int lo = 0, hi = TDIM;
        while (lo < hi) {
            int mid = (lo + hi) >> 1;
            if (binsS[mid] < t) lo = mid + 1; else hi = mid;
        }
        int k = lo - 1;
        k = k < 0 ? 0 : (k > TDIM - 1 ? TDIM - 1 : k);
        const float cdf_at = lds[tid * PITCH + k];
        const float tot = lds[tid * PITCH + (TDIM - 1)];
        const float pmf_at = pmf[(size_t)i * TDIM + k];
        const float surv = tot - cdf_at + pmf_at;
        nllv[tid] = (events[i] == 1) ? -logf(pmf_at + EPS_C) : -logf(surv + EPS_C);
        evv[tid] = events[i];
        scaleA[i] = expf(-cdf_at * SIGMA_INV);
        einvA[i] = expf(cdf_at * SIGMA_INV);
        kidxA[i] = k;
        karr[tid] = k;
    }
    __syncthreads();

    // Column-owner accumulation: k = tid, rows s = 0..31 (deterministic order).
    float acc = 0.f;
    #pragma unroll
    for (int s = 0; s < ROWS; ++s) {
        const float c = lds[s * PITCH + tid];
        if (tid < karr[s]) acc += expf(c * SIGMA_INV);
    }
    SGTp[(size_t)blockIdx.x * TDIM + tid] = acc;   // coalesced

    if (wid == 0) {
        float nv = (lane < ROWS) ? nllv[lane] : 0.f;
        int ev = (lane < ROWS) ? evv[lane] : 0;
        #pragma unroll
        for (int d = 32; d > 0; d >>= 1) {
            nv += __shfl_down(nv, d);
            ev += __shfl_down(ev, d);
        }
        if (lane == 0) { nll_part[blockIdx.x] = nv; ev_part[blockIdx.x] = ev; }
    }
}

// K2: one block per k. Reduce SGTp column; scan kidx once to get
// C_GT = #{k_j > k} and bucket members (k_j == k); exact in-bucket
// correction via einv; write per-bucket rank/npair partials.
__global__ __launch_bounds__(256) void bucket_kernel(
    const float* __restrict__ SGTp, const float* __restrict__ times,
    const int* __restrict__ events, const int* __restrict__ kidx,
    const float* __restrict__ scaleA, const float* __restrict__ einvA,
    float* __restrict__ rank_part, int* __restrict__ npair_part, int N)
{
    __shared__ float red[4];
    __shared__ int redi[4];
    __shared__ int cj[MAXC], oj[MAXC];
    __shared__ float mt[MAXC], me[MAXC];
    __shared__ int ncl_sh;
    __shared__ float SGT_sh;
    __shared__ int CGT_sh;

    const int k = blockIdx.x;
    const int tid = threadIdx.x;
    const int lane = tid & 63;
    const int wid = tid >> 6;

    if (tid == 0) ncl_sh = 0;
    __syncthreads();

    // SGT[k] = sum_b SGTp[b][k]; thread tid handles b = tid (NB == 256).
    float sv = SGTp[(size_t)tid * TDIM + k];
    #pragma unroll
    for (int d = 32; d > 0; d >>= 1) sv += __shfl_down(sv, d);
    if (lane == 0) red[wid] = sv;

    int cnt = 0;
    const int4* kx4 = (const int4*)kidx;
    for (int ch = tid; ch < N / 4; ch += 256) {
        const int4 kx = kx4[ch];
        const int j0 = ch * 4;
        cnt += (kx.x > k) + (kx.y > k) + (kx.z > k) + (kx.w > k);
        if (kx.x == k) { int p = atomicAdd(&ncl_sh, 1); if (p < MAXC) cj[p] = j0 + 0; }
        if (kx.y == k) { int p = atomicAdd(&ncl_sh, 1); if (p < MAXC) cj[p] = j0 + 1; }
        if (kx.z == k) { int p = atomicAdd(&ncl_sh, 1); if (p < MAXC) cj[p] = j0 + 2; }
        if (kx.w == k) { int p = atomicAdd(&ncl_sh, 1); if (p < MAXC) cj[p] = j0 + 3; }
    }
    #pragma unroll
    for (int d = 32; d > 0; d >>= 1) cnt += __shfl_down(cnt, d);
    if (lane == 0) redi[wid] = cnt;
    __syncthreads();
    if (tid == 0) {
        SGT_sh = (red[0] + red[1]) + (red[2] + red[3]);
        CGT_sh = redi[0] + redi[1] + redi[2] + redi[3];
    }
    __syncthreads();

    const int nc = ncl_sh < MAXC ? ncl_sh : MAXC;
    // Rank-reorder members by j (deterministic order despite atomic collection)
    if (tid < nc) {
        const int myj = cj[tid];
        int r = 0;
        for (int m = 0; m < nc; ++m) r += (cj[m] < myj) ? 1 : 0;
        oj[r] = myj;
    }
    __syncthreads();
    if (tid < nc) { mt[tid] = times[oj[tid]]; me[tid] = einvA[oj[tid]]; }
    __syncthreads();

    float pi = 0.f;
    int vf = 0;
    if (tid < nc) {
        const int i = oj[tid];
        const float ti = mt[tid];
        float s = 0.f;
        int c = 0;
        for (int m = 0; m < nc; ++m) {
            if (mt[m] > ti) { s += me[m]; c++; }
        }
        const int C = CGT_sh + c;
        if (events[i] == 1 && C > 0) {
            vf = 1;
            pi = scaleA[i] * (SGT_sh + s) / (float)C;
        }
    }
    #pragma unroll
    for (int d = 32; d > 0; d >>= 1) {
        pi += __shfl_down(pi, d);
        vf += __shfl_down(vf, d);
    }
    __syncthreads();   // red/redi reuse is safe: prior reads fenced above
    if (lane == 0) { red[wid] = pi; redi[wid] = vf; }
    __syncthreads();
    if (tid == 0) {
        rank_part[k] = (red[0] + red[1]) + (red[2] + red[3]);
        npair_part[k] = redi[0] + redi[1] + redi[2] + redi[3];
    }
}

// K3: combine 256 nll/ev partials and 512 rank/npair partials; write scalar.
__global__ __launch_bounds__(512) void final_kernel(
    const float* __restrict__ nll_part, const int* __restrict__ ev_part,
    const float* __restrict__ rank_part, const int* __restrict__ npair_part,
    float* __restrict__ out, int N)
{
    __shared__ double s1[512];
    __shared__ double s2[512];
    __shared__ int i1[512];
    __shared__ int i2[512];
    const int t = threadIdx.x;
    s1[t] = (t < NB) ? (double)nll_part[t] : 0.0;
    i2[t] = (t < NB) ? ev_part[t] : 0;
    s2[t] = (double)rank_part[t];
    i1[t] = npair_part[t];
    __syncthreads();
    for (int off = 256; off > 0; off >>= 1) {
        if (t < off) {
            s1[t] += s1[t + off];
            s2[t] += s2[t + off];
            i1[t] += i1[t + off];
            i2[t] += i2[t + off];
        }
        __syncthreads();
    }
    if (t == 0) {
        double loss = s1[0] / (double)N;
        if (i2[0] > 1 && i1[0] > 0) loss += 0.5 * s2[0] / (double)i1[0];
        out[0] = (float)loss;
    }
}

extern "C" void kernel_launch(void* const* d_in, const int* in_sizes, int n_in,
                              void* d_out, int out_size, void* d_ws, size_t ws_size,
                              hipStream_t stream) {
    const float* pmf = (const float*)d_in[0];
    const float* times = (const float*)d_in[1];
    const int* events = (const int*)d_in[2];
    const float* bins = (const float*)d_in[3];
    const int N = in_sizes[1];  // 8192

    float* SGTp = (float*)d_ws;                      // NB * TDIM
    float* scaleA = SGTp + (size_t)NB * TDIM;        // N
    float* einvA = scaleA + N;                       // N
    float* nll_part = einvA + N;                     // NB
    float* rank_part = nll_part + NB;                // TDIM
    int* kidxA = (int*)(rank_part + TDIM);           // N
    int* ev_part = kidxA + N;                        // NB
    int* npair_part = ev_part + NB;                  // TDIM

    rows_kernel<<<N / ROWS, 512, 0, stream>>>(pmf, times, events, bins,
                                              SGTp, scaleA, einvA, kidxA,
                                              nll_part, ev_part, N);
    bucket_kernel<<<TDIM, 256, 0, stream>>>(SGTp, times, events, kidxA,
                                            scaleA, einvA,
                                            rank_part, npair_part, N);
    final_kernel<<<1, 512, 0, stream>>>(nll_part, ev_part, rank_part,
                                        npair_part, (float*)d_out, N);
}